// Round 1
// baseline (1750.072 us; speedup 1.0000x reference)
//
#include <hip/hip_runtime.h>
#include <hip/hip_bf16.h>

// Problem constants: B=8, N=1024, C=1024, H=16, D=64, M=B*N=8192
#define M_ROWS 8192
#define C_DIM  1024
#define QKV_N  3072

// ---------------------------------------------------------------------------
// GEMM: C[M,N] = A[M,K] @ B[N,K]^T + bias[N]   (both row-major, K contiguous)
// 64x64 tile, BK=32, 256 threads, 4x4 microtile.
// ---------------------------------------------------------------------------
#define TILE_M 64
#define TILE_N 64
#define TILE_K 32

__global__ __launch_bounds__(256) void gemm_bias_nt(
    const float* __restrict__ A, const float* __restrict__ B,
    const float* __restrict__ bias, float* __restrict__ C,
    int M, int N, int K) {
  __shared__ float As[TILE_K][TILE_M];  // As[k][m]
  __shared__ float Bs[TILE_K][TILE_N];  // Bs[k][n]
  const int t  = threadIdx.x;
  const int n0 = blockIdx.x * TILE_N;
  const int m0 = blockIdx.y * TILE_M;
  const int tn = t & 15;   // fast: n-group (lanes 0..15 -> 2-way LDS, free)
  const int tm = t >> 4;   // q-group: 16 lanes share -> broadcast read
  float acc[4][4] = {};

  for (int k0 = 0; k0 < K; k0 += TILE_K) {
    // Stage A,B tiles transposed: 64 rows x 32 k = 512 float4, 2 per thread
#pragma unroll
    for (int u = 0; u < 2; ++u) {
      int f   = t + u * 256;
      int row = f >> 3;
      int kq  = (f & 7) << 2;
      float4 a = *(const float4*)&A[(size_t)(m0 + row) * K + k0 + kq];
      As[kq + 0][row] = a.x; As[kq + 1][row] = a.y;
      As[kq + 2][row] = a.z; As[kq + 3][row] = a.w;
      float4 b = *(const float4*)&B[(size_t)(n0 + row) * K + k0 + kq];
      Bs[kq + 0][row] = b.x; Bs[kq + 1][row] = b.y;
      Bs[kq + 2][row] = b.z; Bs[kq + 3][row] = b.w;
    }
    __syncthreads();
#pragma unroll
    for (int kk = 0; kk < TILE_K; ++kk) {
      float4 av = *(const float4*)&As[kk][tm * 4];  // broadcast within 16-lane grp
      float4 bv = *(const float4*)&Bs[kk][tn * 4];  // 2-way, free
      float a_[4] = {av.x, av.y, av.z, av.w};
      float b_[4] = {bv.x, bv.y, bv.z, bv.w};
#pragma unroll
      for (int i = 0; i < 4; ++i)
#pragma unroll
        for (int j = 0; j < 4; ++j)
          acc[i][j] += a_[i] * b_[j];
    }
    __syncthreads();
  }
  const int n = n0 + tn * 4;
  float4 bz = {bias[n], bias[n + 1], bias[n + 2], bias[n + 3]};
#pragma unroll
  for (int i = 0; i < 4; ++i) {
    int m = m0 + tm * 4 + i;
    float4 o = {acc[i][0] + bz.x, acc[i][1] + bz.y,
                acc[i][2] + bz.z, acc[i][3] + bz.w};
    *(float4*)&C[(size_t)m * N + n] = o;
  }
}

// ---------------------------------------------------------------------------
// RMSNorm in-place on q and k sections of qkv buffer [8192][3072].
// One wave per 64-element head-row. 262144 rows total.
// ---------------------------------------------------------------------------
__global__ __launch_bounds__(256) void rmsnorm_qk(
    float* __restrict__ qkv, const float* __restrict__ qn_w,
    const float* __restrict__ kn_w) {
  int wave = (blockIdx.x * blockDim.x + threadIdx.x) >> 6;
  int lane = threadIdx.x & 63;
  int m  = wave >> 5;      // row in [0, 8192)
  int sh = wave & 31;
  int s  = sh >> 4;        // 0 = q, 1 = k
  int h  = sh & 15;
  const float* w = (s == 0) ? qn_w : kn_w;
  float* p = qkv + (size_t)m * QKV_N + s * C_DIM + h * 64 + lane;
  float v  = *p;
  float ss = v * v;
#pragma unroll
  for (int mask = 32; mask >= 1; mask >>= 1) ss += __shfl_xor(ss, mask);
  float sc = rsqrtf(ss * (1.0f / 64.0f) + 1e-6f);
  *p = v * sc * w[lane];
}

// ---------------------------------------------------------------------------
// Flash attention, fp32. Block = 256 threads, QBLK=64 rows, KBLK=64 keys.
// Grid: (N/64, B*H). LDS = 4 x 16KB = 64KB -> 2 blocks/CU.
// ---------------------------------------------------------------------------
__global__ __launch_bounds__(256) void flash_attn(
    const float* __restrict__ qkv, float* __restrict__ aout) {
  __shared__ float Qs[64][64];  // Qs[d][q]
  __shared__ float Ks[64][64];  // Ks[d][k]
  __shared__ float Vs[64][64];  // Vs[k][d]
  __shared__ float Ps[64][64];  // Ps[k][q]
  const int t  = threadIdx.x;
  const int q0 = blockIdx.x * 64;
  const int bh = blockIdx.y;
  const int b  = bh >> 4, h = bh & 15;
  const size_t base = (size_t)b * 1024 * QKV_N + (size_t)h * 64;
  const float* qp = qkv + base;            // + row*3072 + d
  const float* kp = qkv + base + C_DIM;
  const float* vp = qkv + base + 2 * C_DIM;

  // Stage Q transposed (once)
#pragma unroll
  for (int u = 0; u < 4; ++u) {
    int f = t + u * 256;        // 0..1023
    int row = f >> 4;           // q 0..63
    int dq  = (f & 15) << 2;    // d quad
    float4 a = *(const float4*)&qp[(size_t)(q0 + row) * QKV_N + dq];
    Qs[dq + 0][row] = a.x; Qs[dq + 1][row] = a.y;
    Qs[dq + 2][row] = a.z; Qs[dq + 3][row] = a.w;
  }

  const int tn = t & 15;   // k-group in S phase / d-group in O phase
  const int tq = t >> 4;   // q-group (same rows both phases; 16 lanes share)
  float m_run[4], l_run[4], o[4][4];
#pragma unroll
  for (int r = 0; r < 4; ++r) {
    m_run[r] = -1e30f; l_run[r] = 0.f;
#pragma unroll
    for (int j = 0; j < 4; ++j) o[r][j] = 0.f;
  }
  const float scale = 0.125f;  // 1/sqrt(64)

  for (int k0 = 0; k0 < 1024; k0 += 64) {
    // Stage K (transposed) and V (natural)
#pragma unroll
    for (int u = 0; u < 4; ++u) {
      int f = t + u * 256;
      int row = f >> 4, dq = (f & 15) << 2;
      float4 kv = *(const float4*)&kp[(size_t)(k0 + row) * QKV_N + dq];
      Ks[dq + 0][row] = kv.x; Ks[dq + 1][row] = kv.y;
      Ks[dq + 2][row] = kv.z; Ks[dq + 3][row] = kv.w;
      float4 vv = *(const float4*)&vp[(size_t)(k0 + row) * QKV_N + dq];
      *(float4*)&Vs[row][dq] = vv;
    }
    __syncthreads();

    // S[q][k] = scale * sum_d Q[q][d] K[k][d]
    float s[4][4] = {};
#pragma unroll 8
    for (int d = 0; d < 64; ++d) {
      float4 qv = *(const float4*)&Qs[d][tq * 4];  // broadcast
      float4 kv = *(const float4*)&Ks[d][tn * 4];  // 2-way, free
      float q_[4] = {qv.x, qv.y, qv.z, qv.w};
      float k_[4] = {kv.x, kv.y, kv.z, kv.w};
#pragma unroll
      for (int r = 0; r < 4; ++r)
#pragma unroll
        for (int j = 0; j < 4; ++j)
          s[r][j] += q_[r] * k_[j];
    }

    // Online softmax per q-row (reduce across the 16 lanes sharing tq)
    float corr[4];
#pragma unroll
    for (int r = 0; r < 4; ++r) {
#pragma unroll
      for (int j = 0; j < 4; ++j) s[r][j] *= scale;
      float mx = fmaxf(fmaxf(s[r][0], s[r][1]), fmaxf(s[r][2], s[r][3]));
#pragma unroll
      for (int mask = 8; mask >= 1; mask >>= 1)
        mx = fmaxf(mx, __shfl_xor(mx, mask));
      float m_new = fmaxf(m_run[r], mx);
      corr[r] = __expf(m_run[r] - m_new);
      float rs = 0.f;
#pragma unroll
      for (int j = 0; j < 4; ++j) {
        s[r][j] = __expf(s[r][j] - m_new);
        rs += s[r][j];
      }
#pragma unroll
      for (int mask = 8; mask >= 1; mask >>= 1)
        rs += __shfl_xor(rs, mask);
      l_run[r] = l_run[r] * corr[r] + rs;
      m_run[r] = m_new;
      // Store P transposed: Ps[k][q]
#pragma unroll
      for (int j = 0; j < 4; ++j)
        Ps[tn * 4 + j][tq * 4 + r] = s[r][j];
    }
    __syncthreads();

    // O[q][d] = sum_k P[q][k] V[k][d]; rescale accumulator first
#pragma unroll
    for (int r = 0; r < 4; ++r)
#pragma unroll
      for (int j = 0; j < 4; ++j) o[r][j] *= corr[r];
#pragma unroll 8
    for (int k = 0; k < 64; ++k) {
      float4 pv = *(const float4*)&Ps[k][tq * 4];  // broadcast
      float4 vv = *(const float4*)&Vs[k][tn * 4];  // 2-way, free
      float p_[4] = {pv.x, pv.y, pv.z, pv.w};
      float v_[4] = {vv.x, vv.y, vv.z, vv.w};
#pragma unroll
      for (int r = 0; r < 4; ++r)
#pragma unroll
        for (int j = 0; j < 4; ++j)
          o[r][j] += p_[r] * v_[j];
    }
    __syncthreads();
  }

  // Write attn-out in [m][h*64+d] layout (ready for proj GEMM)
#pragma unroll
  for (int r = 0; r < 4; ++r) {
    int q = q0 + tq * 4 + r;
    float inv = 1.0f / l_run[r];
    float4 ov = {o[r][0] * inv, o[r][1] * inv, o[r][2] * inv, o[r][3] * inv};
    *(float4*)&aout[((size_t)b * 1024 + q) * C_DIM + h * 64 + tn * 4] = ov;
  }
}

// ---------------------------------------------------------------------------
extern "C" void kernel_launch(void* const* d_in, const int* in_sizes, int n_in,
                              void* d_out, int out_size, void* d_ws, size_t ws_size,
                              hipStream_t stream) {
  const float* x      = (const float*)d_in[0];
  const float* w_qkv  = (const float*)d_in[1];
  const float* b_qkv  = (const float*)d_in[2];
  const float* qn_w   = (const float*)d_in[3];
  const float* kn_w   = (const float*)d_in[4];
  const float* w_proj = (const float*)d_in[5];
  const float* b_proj = (const float*)d_in[6];
  float* out = (float*)d_out;

  // ws: qkv [8192*3072] fp32 (96MB) + attn-out [8192*1024] fp32 (32MB) = 128MB
  float* qkv  = (float*)d_ws;
  float* aout = qkv + (size_t)M_ROWS * QKV_N;

  // 1) QKV projection
  gemm_bias_nt<<<dim3(QKV_N / TILE_N, M_ROWS / TILE_M), 256, 0, stream>>>(
      x, w_qkv, b_qkv, qkv, M_ROWS, QKV_N, C_DIM);
  // 2) RMSNorm q,k (in place)
  rmsnorm_qk<<<(M_ROWS * 32) / 4, 256, 0, stream>>>(qkv, qn_w, kn_w);
  // 3) Flash attention
  flash_attn<<<dim3(16, 128), 256, 0, stream>>>(qkv, aout);
  // 4) Output projection
  gemm_bias_nt<<<dim3(C_DIM / TILE_N, M_ROWS / TILE_M), 256, 0, stream>>>(
      aout, w_proj, b_proj, out, M_ROWS, C_DIM, C_DIM);
}

// Round 2
// 974.980 us; speedup vs baseline: 1.7950x; 1.7950x over previous
//
#include <hip/hip_runtime.h>
#include <hip/hip_bf16.h>
#include <stdint.h>

// Problem constants: B=8, N=1024, C=1024, H=16, D=64, M=B*N=8192
#define M_ROWS 8192
#define C_DIM  1024
#define QKV_N  3072

typedef __attribute__((ext_vector_type(8))) short short8_t;   // 8 bf16 (4 VGPRs)
typedef __attribute__((ext_vector_type(4))) float float4_t;   // 4 fp32 acc
typedef unsigned short u16;
typedef unsigned int u32;

__device__ __forceinline__ u16 f32_to_bf16(float f) {
  u32 u = __float_as_uint(f);
  u32 r = (u + 0x7fffu + ((u >> 16) & 1u)) >> 16;  // RNE
  return (u16)r;
}
__device__ __forceinline__ float bf16_to_f32(u16 h) {
  return __uint_as_float((u32)h << 16);
}
__device__ __forceinline__ void gld_lds16(const void* g, void* l) {
  __builtin_amdgcn_global_load_lds(
      (const __attribute__((address_space(1))) u32*)g,
      (__attribute__((address_space(3))) u32*)l, 16, 0, 0);
}

// ---------------------------------------------------------------------------
// split fp32 -> (hi, lo) bf16 pair; 4 elems/thread
// ---------------------------------------------------------------------------
__global__ __launch_bounds__(256) void split_bf16(
    const float* __restrict__ in, u16* __restrict__ hi, u16* __restrict__ lo) {
  int i = blockIdx.x * 256 + threadIdx.x;
  float4 v = ((const float4*)in)[i];
  float x[4] = {v.x, v.y, v.z, v.w};
  union { u16 u[4]; uint2 v2; } H, L;
#pragma unroll
  for (int j = 0; j < 4; ++j) {
    u16 h = f32_to_bf16(x[j]);
    H.u[j] = h;
    L.u[j] = f32_to_bf16(x[j] - bf16_to_f32(h));
  }
  ((uint2*)hi)[i] = H.v2;
  ((uint2*)lo)[i] = L.v2;
}

// ---------------------------------------------------------------------------
// Split-bf16 MFMA GEMM: C[M,N] = (Ah+Al)[M,K] @ (Bh+Bl)[N,K]^T + bias[N]
// (drops Al*Bl). 128x128 tile, BK=32, 256 thr (4 waves, 2x2), 16x16x32 MFMA.
// m97 structure: global_load_lds width 16, linear LDS, 2-barrier K-loop.
// ---------------------------------------------------------------------------
__global__ __launch_bounds__(256) void gemm_split_mfma(
    const u16* __restrict__ Ah, const u16* __restrict__ Al,
    const u16* __restrict__ Bh, const u16* __restrict__ Bl,
    const float* __restrict__ bias, float* __restrict__ C,
    int M, int N, int K) {
  __shared__ u16 sAh[128 * 32], sAl[128 * 32], sBh[128 * 32], sBl[128 * 32];
  const int t = threadIdx.x;
  const int wv = t >> 6;
  const int lane = t & 63;
  const int n0 = blockIdx.x * 128;
  const int m0 = blockIdx.y * 128;
  const int wm = wv >> 1, wn = wv & 1;      // wave 2x2 grid, each 64x64 out
  const int fr = lane & 15;                 // frag row (A) / col (B)
  const int kfr = (lane >> 4) * 8;          // frag k-chunk

  float4_t acc[4][4];
  const float4_t zero = {0.f, 0.f, 0.f, 0.f};
#pragma unroll
  for (int i = 0; i < 4; ++i)
#pragma unroll
    for (int j = 0; j < 4; ++j) acc[i][j] = zero;

  for (int k0 = 0; k0 < K; k0 += 32) {
    // Stage 4 tiles of [128][32] bf16 (8KB each) via 16B global_load_lds.
    // flat idx -> LDS elem idx*8 == row*32 + ke  (linear row-major, no pad)
#pragma unroll
    for (int u = 0; u < 2; ++u) {
      int idx = u * 256 + t;
      int row = idx >> 2;
      int ke = (idx & 3) * 8;
      int ldsoff = (u * 256 + wv * 64) * 8;  // wave-uniform base (elems)
      const size_t ga = (size_t)(m0 + row) * K + k0 + ke;
      const size_t gb = (size_t)(n0 + row) * K + k0 + ke;
      gld_lds16(Ah + ga, sAh + ldsoff);
      gld_lds16(Al + ga, sAl + ldsoff);
      gld_lds16(Bh + gb, sBh + ldsoff);
      gld_lds16(Bl + gb, sBl + ldsoff);
    }
    __syncthreads();

    short8_t ah[4], al[4], bh[4], bl[4];
#pragma unroll
    for (int i = 0; i < 4; ++i) {
      ah[i] = *(const short8_t*)&sAh[(wm * 64 + i * 16 + fr) * 32 + kfr];
      al[i] = *(const short8_t*)&sAl[(wm * 64 + i * 16 + fr) * 32 + kfr];
      bh[i] = *(const short8_t*)&sBh[(wn * 64 + i * 16 + fr) * 32 + kfr];
      bl[i] = *(const short8_t*)&sBl[(wn * 64 + i * 16 + fr) * 32 + kfr];
    }
#pragma unroll
    for (int i = 0; i < 4; ++i)
#pragma unroll
      for (int j = 0; j < 4; ++j) {
        acc[i][j] = __builtin_amdgcn_mfma_f32_16x16x32_bf16(ah[i], bh[j], acc[i][j], 0, 0, 0);
        acc[i][j] = __builtin_amdgcn_mfma_f32_16x16x32_bf16(ah[i], bl[j], acc[i][j], 0, 0, 0);
        acc[i][j] = __builtin_amdgcn_mfma_f32_16x16x32_bf16(al[i], bh[j], acc[i][j], 0, 0, 0);
      }
    __syncthreads();
  }

  // Epilogue: C/D layout col=lane&15, row=(lane>>4)*4+reg  [m89/m91]
  const int r0 = (lane >> 4) * 4;
#pragma unroll
  for (int j = 0; j < 4; ++j) {
    int n = n0 + wn * 64 + j * 16 + fr;
    float bz = bias[n];
#pragma unroll
    for (int i = 0; i < 4; ++i) {
      int mb = m0 + wm * 64 + i * 16 + r0;
#pragma unroll
      for (int r = 0; r < 4; ++r)
        C[(size_t)(mb + r) * N + n] = acc[i][j][r] + bz;
    }
  }
}

// ---------------------------------------------------------------------------
// RMSNorm in-place on q and k sections of qkv buffer [8192][3072].
// ---------------------------------------------------------------------------
__global__ __launch_bounds__(256) void rmsnorm_qk(
    float* __restrict__ qkv, const float* __restrict__ qn_w,
    const float* __restrict__ kn_w) {
  int wave = (blockIdx.x * blockDim.x + threadIdx.x) >> 6;
  int lane = threadIdx.x & 63;
  int m  = wave >> 5;
  int sh = wave & 31;
  int s  = sh >> 4;
  int h  = sh & 15;
  const float* w = (s == 0) ? qn_w : kn_w;
  float* p = qkv + (size_t)m * QKV_N + s * C_DIM + h * 64 + lane;
  float v  = *p;
  float ss = v * v;
#pragma unroll
  for (int mask = 32; mask >= 1; mask >>= 1) ss += __shfl_xor(ss, mask);
  float sc = rsqrtf(ss * (1.0f / 64.0f) + 1e-6f);
  *p = v * sc * w[lane];
}

// ---------------------------------------------------------------------------
// Flash attention, fp32 VALU. Epilogue emits bf16 hi/lo split of attn-out.
// ---------------------------------------------------------------------------
__global__ __launch_bounds__(256) void flash_attn(
    const float* __restrict__ qkv, u16* __restrict__ ao_hi,
    u16* __restrict__ ao_lo) {
  __shared__ float Qs[64][64];  // Qs[d][q]
  __shared__ float Ks[64][64];  // Ks[d][k]
  __shared__ float Vs[64][64];  // Vs[k][d]
  __shared__ float Ps[64][64];  // Ps[k][q]
  const int t  = threadIdx.x;
  const int q0 = blockIdx.x * 64;
  const int bh = blockIdx.y;
  const int b  = bh >> 4, h = bh & 15;
  const size_t base = (size_t)b * 1024 * QKV_N + (size_t)h * 64;
  const float* qp = qkv + base;
  const float* kp = qkv + base + C_DIM;
  const float* vp = qkv + base + 2 * C_DIM;

#pragma unroll
  for (int u = 0; u < 4; ++u) {
    int f = t + u * 256;
    int row = f >> 4;
    int dq  = (f & 15) << 2;
    float4 a = *(const float4*)&qp[(size_t)(q0 + row) * QKV_N + dq];
    Qs[dq + 0][row] = a.x; Qs[dq + 1][row] = a.y;
    Qs[dq + 2][row] = a.z; Qs[dq + 3][row] = a.w;
  }

  const int tn = t & 15;
  const int tq = t >> 4;
  float m_run[4], l_run[4], o[4][4];
#pragma unroll
  for (int r = 0; r < 4; ++r) {
    m_run[r] = -1e30f; l_run[r] = 0.f;
#pragma unroll
    for (int j = 0; j < 4; ++j) o[r][j] = 0.f;
  }
  const float scale = 0.125f;

  for (int k0 = 0; k0 < 1024; k0 += 64) {
#pragma unroll
    for (int u = 0; u < 4; ++u) {
      int f = t + u * 256;
      int row = f >> 4, dq = (f & 15) << 2;
      float4 kv = *(const float4*)&kp[(size_t)(k0 + row) * QKV_N + dq];
      Ks[dq + 0][row] = kv.x; Ks[dq + 1][row] = kv.y;
      Ks[dq + 2][row] = kv.z; Ks[dq + 3][row] = kv.w;
      float4 vv = *(const float4*)&vp[(size_t)(k0 + row) * QKV_N + dq];
      *(float4*)&Vs[row][dq] = vv;
    }
    __syncthreads();

    float s[4][4] = {};
#pragma unroll 8
    for (int d = 0; d < 64; ++d) {
      float4 qv = *(const float4*)&Qs[d][tq * 4];
      float4 kv = *(const float4*)&Ks[d][tn * 4];
      float q_[4] = {qv.x, qv.y, qv.z, qv.w};
      float k_[4] = {kv.x, kv.y, kv.z, kv.w};
#pragma unroll
      for (int r = 0; r < 4; ++r)
#pragma unroll
        for (int j = 0; j < 4; ++j)
          s[r][j] += q_[r] * k_[j];
    }

    float corr[4];
#pragma unroll
    for (int r = 0; r < 4; ++r) {
#pragma unroll
      for (int j = 0; j < 4; ++j) s[r][j] *= scale;
      float mx = fmaxf(fmaxf(s[r][0], s[r][1]), fmaxf(s[r][2], s[r][3]));
#pragma unroll
      for (int mask = 8; mask >= 1; mask >>= 1)
        mx = fmaxf(mx, __shfl_xor(mx, mask));
      float m_new = fmaxf(m_run[r], mx);
      corr[r] = __expf(m_run[r] - m_new);
      float rs = 0.f;
#pragma unroll
      for (int j = 0; j < 4; ++j) {
        s[r][j] = __expf(s[r][j] - m_new);
        rs += s[r][j];
      }
#pragma unroll
      for (int mask = 8; mask >= 1; mask >>= 1)
        rs += __shfl_xor(rs, mask);
      l_run[r] = l_run[r] * corr[r] + rs;
      m_run[r] = m_new;
#pragma unroll
      for (int j = 0; j < 4; ++j)
        Ps[tn * 4 + j][tq * 4 + r] = s[r][j];
    }
    __syncthreads();

#pragma unroll
    for (int r = 0; r < 4; ++r)
#pragma unroll
      for (int j = 0; j < 4; ++j) o[r][j] *= corr[r];
#pragma unroll 8
    for (int k = 0; k < 64; ++k) {
      float4 pv = *(const float4*)&Ps[k][tq * 4];
      float4 vv = *(const float4*)&Vs[k][tn * 4];
      float p_[4] = {pv.x, pv.y, pv.z, pv.w};
      float v_[4] = {vv.x, vv.y, vv.z, vv.w};
#pragma unroll
      for (int r = 0; r < 4; ++r)
#pragma unroll
        for (int j = 0; j < 4; ++j)
          o[r][j] += p_[r] * v_[j];
    }
    __syncthreads();
  }

  // Write attn-out split into bf16 hi/lo, layout [m][h*64+d]
#pragma unroll
  for (int r = 0; r < 4; ++r) {
    int q = q0 + tq * 4 + r;
    float inv = 1.0f / l_run[r];
    union { u16 u[4]; uint2 v2; } H, L;
#pragma unroll
    for (int j = 0; j < 4; ++j) {
      float v = o[r][j] * inv;
      u16 hb = f32_to_bf16(v);
      H.u[j] = hb;
      L.u[j] = f32_to_bf16(v - bf16_to_f32(hb));
    }
    size_t off = ((size_t)b * 1024 + q) * C_DIM + h * 64 + tn * 4;
    *(uint2*)&ao_hi[off] = H.v2;
    *(uint2*)&ao_lo[off] = L.v2;
  }
}

// ---------------------------------------------------------------------------
extern "C" void kernel_launch(void* const* d_in, const int* in_sizes, int n_in,
                              void* d_out, int out_size, void* d_ws, size_t ws_size,
                              hipStream_t stream) {
  const float* x      = (const float*)d_in[0];
  const float* w_qkv  = (const float*)d_in[1];
  const float* b_qkv  = (const float*)d_in[2];
  const float* qn_w   = (const float*)d_in[3];
  const float* kn_w   = (const float*)d_in[4];
  const float* w_proj = (const float*)d_in[5];
  const float* b_proj = (const float*)d_in[6];
  float* out = (float*)d_out;

  // ws layout:
  //   qkv fp32 [8192*3072]                     = 100663296 B
  //   then u16 buffers (hi/lo pairs)
  char* wsb = (char*)d_ws;
  float* qkv = (float*)wsb;
  u16* x_hi  = (u16*)(wsb + (size_t)100663296);
  u16* x_lo  = x_hi + 8388608;
  u16* wq_hi = x_lo + 8388608;
  u16* wq_lo = wq_hi + 3145728;
  u16* wp_hi = wq_lo + 3145728;
  u16* wp_lo = wp_hi + 1048576;
  u16* ao_hi = wp_lo + 1048576;
  u16* ao_lo = ao_hi + 8388608;

  // 0) hi/lo decompositions
  split_bf16<<<8192, 256, 0, stream>>>(x, x_hi, x_lo);
  split_bf16<<<3072, 256, 0, stream>>>(w_qkv, wq_hi, wq_lo);
  split_bf16<<<1024, 256, 0, stream>>>(w_proj, wp_hi, wp_lo);

  // 1) QKV projection (fp32 out)
  gemm_split_mfma<<<dim3(QKV_N / 128, M_ROWS / 128), 256, 0, stream>>>(
      x_hi, x_lo, wq_hi, wq_lo, b_qkv, qkv, M_ROWS, QKV_N, C_DIM);
  // 2) RMSNorm q,k (in place)
  rmsnorm_qk<<<(M_ROWS * 32) / 4, 256, 0, stream>>>(qkv, qn_w, kn_w);
  // 3) Flash attention (fp32, emits bf16 hi/lo attn-out)
  flash_attn<<<dim3(16, 128), 256, 0, stream>>>(qkv, ao_hi, ao_lo);
  // 4) Output projection
  gemm_split_mfma<<<dim3(C_DIM / 128, M_ROWS / 128), 256, 0, stream>>>(
      ao_hi, ao_lo, wp_hi, wp_lo, b_proj, out, M_ROWS, C_DIM, C_DIM);
}

// Round 3
// 495.958 us; speedup vs baseline: 3.5287x; 1.9659x over previous
//
#include <hip/hip_runtime.h>
#include <hip/hip_bf16.h>
#include <stdint.h>

// Problem constants: B=8, N=1024, C=1024, H=16, D=64, M=B*N=8192
#define M_ROWS 8192
#define C_DIM  1024
#define QKV_N  3072

typedef __attribute__((ext_vector_type(8))) short short8_t;   // 8 bf16 (4 VGPRs)
typedef __attribute__((ext_vector_type(4))) float float4_t;   // 4 fp32 acc
typedef unsigned short u16;
typedef unsigned int u32;

__device__ __forceinline__ u16 f32_to_bf16(float f) {
  u32 u = __float_as_uint(f);
  u32 r = (u + 0x7fffu + ((u >> 16) & 1u)) >> 16;  // RNE
  return (u16)r;
}
__device__ __forceinline__ float bf16_to_f32(u16 h) {
  return __uint_as_float((u32)h << 16);
}
__device__ __forceinline__ void gld_lds16(const void* g, void* l) {
  __builtin_amdgcn_global_load_lds(
      (const __attribute__((address_space(1))) u32*)g,
      (__attribute__((address_space(3))) u32*)l, 16, 0, 0);
}
// Swizzled elem offset in a [64][64]-bf16 LDS tile (row len 128B):
// byte ^= ((row&7)<<4)  <=>  elem ^= ((row&7)<<3)
__device__ __forceinline__ int elem_off(int row, int e0) {
  return row * 64 + (e0 ^ ((row & 7) << 3));
}

// ---------------------------------------------------------------------------
// split fp32 -> (hi, lo) bf16 pair; 4 elems/thread
// ---------------------------------------------------------------------------
__global__ __launch_bounds__(256) void split_bf16(
    const float* __restrict__ in, u16* __restrict__ hi, u16* __restrict__ lo) {
  int i = blockIdx.x * 256 + threadIdx.x;
  float4 v = ((const float4*)in)[i];
  float x[4] = {v.x, v.y, v.z, v.w};
  union { u16 u[4]; uint2 v2; } H, L;
#pragma unroll
  for (int j = 0; j < 4; ++j) {
    u16 h = f32_to_bf16(x[j]);
    H.u[j] = h;
    L.u[j] = f32_to_bf16(x[j] - bf16_to_f32(h));
  }
  ((uint2*)hi)[i] = H.v2;
  ((uint2*)lo)[i] = L.v2;
}

// ---------------------------------------------------------------------------
// Split-bf16 MFMA GEMM (Ah+Al)@(Bh+Bl)^T + bias, drops Al*Bl.
// Output C stride fixed 1024; 3 section pointers (QKV writes q/k/v separately).
// ---------------------------------------------------------------------------
__global__ __launch_bounds__(256) void gemm_split_mfma(
    const u16* __restrict__ Ah, const u16* __restrict__ Al,
    const u16* __restrict__ Bh, const u16* __restrict__ Bl,
    const float* __restrict__ bias,
    float* __restrict__ O0, float* __restrict__ O1, float* __restrict__ O2,
    int M, int N, int K) {
  __shared__ u16 sAh[128 * 32], sAl[128 * 32], sBh[128 * 32], sBl[128 * 32];
  const int t = threadIdx.x;
  const int wv = t >> 6;
  const int lane = t & 63;
  const int n0 = blockIdx.x * 128;
  const int m0 = blockIdx.y * 128;
  const int wm = wv >> 1, wn = wv & 1;
  const int fr = lane & 15;
  const int kfr = (lane >> 4) * 8;
  const int sec = blockIdx.x >> 3;  // n0>>10: output section (0/1/2)
  float* __restrict__ Cout = (sec == 0) ? O0 : ((sec == 1) ? O1 : O2);

  float4_t acc[4][4];
  const float4_t zero = {0.f, 0.f, 0.f, 0.f};
#pragma unroll
  for (int i = 0; i < 4; ++i)
#pragma unroll
    for (int j = 0; j < 4; ++j) acc[i][j] = zero;

  for (int k0 = 0; k0 < K; k0 += 32) {
#pragma unroll
    for (int u = 0; u < 2; ++u) {
      int idx = u * 256 + t;
      int row = idx >> 2;
      int ke = (idx & 3) * 8;
      int ldsoff = (u * 256 + wv * 64) * 8;
      const size_t ga = (size_t)(m0 + row) * K + k0 + ke;
      const size_t gb = (size_t)(n0 + row) * K + k0 + ke;
      gld_lds16(Ah + ga, sAh + ldsoff);
      gld_lds16(Al + ga, sAl + ldsoff);
      gld_lds16(Bh + gb, sBh + ldsoff);
      gld_lds16(Bl + gb, sBl + ldsoff);
    }
    __syncthreads();

    short8_t ah[4], al[4], bh[4], bl[4];
#pragma unroll
    for (int i = 0; i < 4; ++i) {
      ah[i] = *(const short8_t*)&sAh[(wm * 64 + i * 16 + fr) * 32 + kfr];
      al[i] = *(const short8_t*)&sAl[(wm * 64 + i * 16 + fr) * 32 + kfr];
      bh[i] = *(const short8_t*)&sBh[(wn * 64 + i * 16 + fr) * 32 + kfr];
      bl[i] = *(const short8_t*)&sBl[(wn * 64 + i * 16 + fr) * 32 + kfr];
    }
#pragma unroll
    for (int i = 0; i < 4; ++i)
#pragma unroll
      for (int j = 0; j < 4; ++j) {
        acc[i][j] = __builtin_amdgcn_mfma_f32_16x16x32_bf16(ah[i], bh[j], acc[i][j], 0, 0, 0);
        acc[i][j] = __builtin_amdgcn_mfma_f32_16x16x32_bf16(ah[i], bl[j], acc[i][j], 0, 0, 0);
        acc[i][j] = __builtin_amdgcn_mfma_f32_16x16x32_bf16(al[i], bh[j], acc[i][j], 0, 0, 0);
      }
    __syncthreads();
  }

  const int r0 = (lane >> 4) * 4;
#pragma unroll
  for (int j = 0; j < 4; ++j) {
    int n = n0 + wn * 64 + j * 16 + fr;
    float bz = bias[n];
    int col = n & 1023;
#pragma unroll
    for (int i = 0; i < 4; ++i) {
      int mb = m0 + wm * 64 + i * 16 + r0;
#pragma unroll
      for (int r = 0; r < 4; ++r)
        Cout[(size_t)(mb + r) * 1024 + col] = acc[i][j][r] + bz;
    }
  }
}

// ---------------------------------------------------------------------------
// RMSNorm over 64-elem head rows of src [8192][1024]; emit bf16 hi/lo.
// ---------------------------------------------------------------------------
__global__ __launch_bounds__(256) void rms_split(
    const float* __restrict__ src, const float* __restrict__ w,
    u16* __restrict__ hi, u16* __restrict__ lo) {
  int wave = (blockIdx.x * 256 + threadIdx.x) >> 6;
  int lane = threadIdx.x & 63;
  int m = wave >> 4, h = wave & 15;
  size_t off = (size_t)m * 1024 + h * 64 + lane;
  float v = src[off];
  float ss = v * v;
#pragma unroll
  for (int mask = 32; mask >= 1; mask >>= 1) ss += __shfl_xor(ss, mask);
  float sc = rsqrtf(ss * (1.0f / 64.0f) + 1e-6f);
  float vn = v * sc * w[lane];
  u16 hb = f32_to_bf16(vn);
  hi[off] = hb;
  lo[off] = f32_to_bf16(vn - bf16_to_f32(hb));
}

// ---------------------------------------------------------------------------
// V transpose: vf32 [8192][1024] -> vt bf16 [bh=128][d=64][n=1024]
// ---------------------------------------------------------------------------
__global__ __launch_bounds__(256) void vtrans(const float* __restrict__ vf32,
                                              u16* __restrict__ vt) {
  __shared__ float T[64][65];
  const int t = threadIdx.x;
  const int nb = blockIdx.x;   // 16 n-tiles
  const int bh = blockIdx.y;   // 128
  const int b = bh >> 4, h = bh & 15;
  const int n0 = nb * 64;
#pragma unroll
  for (int u = 0; u < 4; ++u) {
    int idx = u * 256 + t;
    int row = idx >> 4;
    int dq = (idx & 15) << 2;
    float4 v = *(const float4*)&vf32[((size_t)(b * 1024 + n0 + row)) * 1024 + h * 64 + dq];
    T[row][dq + 0] = v.x; T[row][dq + 1] = v.y;
    T[row][dq + 2] = v.z; T[row][dq + 3] = v.w;
  }
  __syncthreads();
#pragma unroll
  for (int u = 0; u < 2; ++u) {
    int idx = u * 256 + t;
    int d = idx >> 3, c8 = (idx & 7) * 8;
    union { u16 q[8]; uint4 v4; } P;
#pragma unroll
    for (int i = 0; i < 8; ++i) P.q[i] = f32_to_bf16(T[c8 + i][d]);
    *(uint4*)&vt[((size_t)bh * 64 + d) * 1024 + n0 + c8] = P.v4;
  }
}

// ---------------------------------------------------------------------------
// MFMA flash attention. QBLK=64 (4 waves x 16 rows), KBLK=64, D=64.
// QK^T split-bf16 (3 MFMA), PV plain bf16. All LDS tiles [64][64] bf16 with
// XOR swizzle (pre-swizzled global source, linear global_load_lds dest).
// ---------------------------------------------------------------------------
__device__ __forceinline__ void stage_tile64(const u16* __restrict__ src,
                                             u16* __restrict__ lds, int t,
                                             int rowbase, size_t stride,
                                             int colbase) {
#pragma unroll
  for (int u = 0; u < 2; ++u) {
    int idx = u * 256 + t;
    int row = idx >> 3;
    int cs = (idx & 7) ^ (row & 7);  // inverse-swizzled source chunk
    gld_lds16(src + (size_t)(rowbase + row) * stride + colbase + cs * 8,
              lds + (size_t)(u * 256 + (t >> 6) * 64) * 8);
  }
}

__global__ __launch_bounds__(256) void flash_mfma(
    const u16* __restrict__ qh, const u16* __restrict__ ql,
    const u16* __restrict__ kh, const u16* __restrict__ kl,
    const u16* __restrict__ vt, u16* __restrict__ ao_hi,
    u16* __restrict__ ao_lo) {
  __shared__ __align__(16) u16 sQh[4096], sQl[4096], sKh[4096], sKl[4096],
      sVt[4096], sPs[4096];
  const int t = threadIdx.x;
  const int wv = t >> 6, lane = t & 63;
  const int fr = lane & 15;   // frag row/col
  const int g = lane >> 4;    // k-chunk group
  const int q0 = blockIdx.x * 64;
  const int bh = blockIdx.y;
  const int b = bh >> 4, h = bh & 15;
  const u16* qhbase = qh + (size_t)b * 1024 * 1024 + h * 64;
  const u16* qlbase = ql + (size_t)b * 1024 * 1024 + h * 64;
  const u16* khbase = kh + (size_t)b * 1024 * 1024 + h * 64;
  const u16* klbase = kl + (size_t)b * 1024 * 1024 + h * 64;
  const u16* vbase = vt + (size_t)bh * 64 * 1024;

  // Stage Q hi/lo once (visible after first barrier)
  stage_tile64(qhbase, sQh, t, q0, 1024, 0);
  stage_tile64(qlbase, sQl, t, q0, 1024, 0);

  short8_t aQh[2] = {}, aQl[2] = {};
  float m_run[4], l_run[4];
  float4_t o[4];
  const float4_t zero = {0.f, 0.f, 0.f, 0.f};
#pragma unroll
  for (int r = 0; r < 4; ++r) { m_run[r] = -1e30f; l_run[r] = 0.f; }
#pragma unroll
  for (int dt = 0; dt < 4; ++dt) o[dt] = zero;
  const float scale = 0.125f;

  for (int k0 = 0; k0 < 1024; k0 += 64) {
    stage_tile64(khbase, sKh, t, k0, 1024, 0);
    stage_tile64(klbase, sKl, t, k0, 1024, 0);
    stage_tile64(vbase, sVt, t, 0, 1024, k0);
    __syncthreads();

    if (k0 == 0) {
#pragma unroll
      for (int c = 0; c < 2; ++c) {
        aQh[c] = *(const short8_t*)&sQh[elem_off(wv * 16 + fr, c * 32 + g * 8)];
        aQl[c] = *(const short8_t*)&sQl[elem_off(wv * 16 + fr, c * 32 + g * 8)];
      }
    }

    // S = Qh*Kh + Qh*Kl + Ql*Kh  (split-bf16)
    float4_t sac[4];
#pragma unroll
    for (int j = 0; j < 4; ++j) sac[j] = zero;
#pragma unroll
    for (int j = 0; j < 4; ++j)
#pragma unroll
      for (int c = 0; c < 2; ++c) {
        short8_t kh_ = *(const short8_t*)&sKh[elem_off(j * 16 + fr, c * 32 + g * 8)];
        short8_t kl_ = *(const short8_t*)&sKl[elem_off(j * 16 + fr, c * 32 + g * 8)];
        sac[j] = __builtin_amdgcn_mfma_f32_16x16x32_bf16(aQh[c], kh_, sac[j], 0, 0, 0);
        sac[j] = __builtin_amdgcn_mfma_f32_16x16x32_bf16(aQh[c], kl_, sac[j], 0, 0, 0);
        sac[j] = __builtin_amdgcn_mfma_f32_16x16x32_bf16(aQl[c], kh_, sac[j], 0, 0, 0);
      }

    // Online softmax; D-layout: q = wv*16 + g*4 + r, col = k = k0 + j*16 + fr
    float corr[4];
#pragma unroll
    for (int r = 0; r < 4; ++r) {
      float p0 = sac[0][r] * scale, p1 = sac[1][r] * scale;
      float p2 = sac[2][r] * scale, p3 = sac[3][r] * scale;
      float mx = fmaxf(fmaxf(p0, p1), fmaxf(p2, p3));
#pragma unroll
      for (int mask = 8; mask >= 1; mask >>= 1)
        mx = fmaxf(mx, __shfl_xor(mx, mask));
      float m_new = fmaxf(m_run[r], mx);
      corr[r] = __expf(m_run[r] - m_new);
      p0 = __expf(p0 - m_new); p1 = __expf(p1 - m_new);
      p2 = __expf(p2 - m_new); p3 = __expf(p3 - m_new);
      float rs = p0 + p1 + p2 + p3;
#pragma unroll
      for (int mask = 8; mask >= 1; mask >>= 1) rs += __shfl_xor(rs, mask);
      l_run[r] = l_run[r] * corr[r] + rs;
      m_run[r] = m_new;
      int qloc = wv * 16 + g * 4 + r;
      int sw = (qloc & 7) << 3;
      sPs[qloc * 64 + ((0 * 16 + fr) ^ sw)] = f32_to_bf16(p0);
      sPs[qloc * 64 + ((1 * 16 + fr) ^ sw)] = f32_to_bf16(p1);
      sPs[qloc * 64 + ((2 * 16 + fr) ^ sw)] = f32_to_bf16(p2);
      sPs[qloc * 64 + ((3 * 16 + fr) ^ sw)] = f32_to_bf16(p3);
    }
    // Rescale O accumulator
#pragma unroll
    for (int dt = 0; dt < 4; ++dt)
#pragma unroll
      for (int r = 0; r < 4; ++r) o[dt][r] *= corr[r];

    // PV: A = this wave's own P rows (intra-wave dep -> no barrier), B = Vt
    short8_t pa[2];
#pragma unroll
    for (int c = 0; c < 2; ++c)
      pa[c] = *(const short8_t*)&sPs[elem_off(wv * 16 + fr, c * 32 + g * 8)];
#pragma unroll
    for (int dt = 0; dt < 4; ++dt)
#pragma unroll
      for (int c = 0; c < 2; ++c) {
        short8_t vb = *(const short8_t*)&sVt[elem_off(dt * 16 + fr, c * 32 + g * 8)];
        o[dt] = __builtin_amdgcn_mfma_f32_16x16x32_bf16(pa[c], vb, o[dt], 0, 0, 0);
      }
    __syncthreads();
  }

  // Epilogue: normalize, split hi/lo, write [m][h*64+d]
#pragma unroll
  for (int r = 0; r < 4; ++r) {
    float inv = 1.0f / l_run[r];
    int q = q0 + wv * 16 + g * 4 + r;
#pragma unroll
    for (int dt = 0; dt < 4; ++dt) {
      float v = o[dt][r] * inv;
      u16 hb = f32_to_bf16(v);
      size_t off = ((size_t)b * 1024 + q) * 1024 + h * 64 + dt * 16 + fr;
      ao_hi[off] = hb;
      ao_lo[off] = f32_to_bf16(v - bf16_to_f32(hb));
    }
  }
}

// ---------------------------------------------------------------------------
extern "C" void kernel_launch(void* const* d_in, const int* in_sizes, int n_in,
                              void* d_out, int out_size, void* d_ws, size_t ws_size,
                              hipStream_t stream) {
  const float* x      = (const float*)d_in[0];
  const float* w_qkv  = (const float*)d_in[1];
  const float* b_qkv  = (const float*)d_in[2];
  const float* qn_w   = (const float*)d_in[3];
  const float* kn_w   = (const float*)d_in[4];
  const float* w_proj = (const float*)d_in[5];
  const float* b_proj = (const float*)d_in[6];
  float* out = (float*)d_out;

  // ws layout (176MB) with lifetime-based aliasing:
  char* wsb = (char*)d_ws;
  float* qf32 = (float*)wsb;                     // 32MB, dead after rms_q
  float* kf32 = qf32 + 8388608;                  // 32MB, dead after rms_k
  float* vf32 = kf32 + 8388608;                  // 32MB, dead after vtrans
  u16* x_hi  = (u16*)(vf32 + 8388608);           // 16MB, dead after QKV gemm
  u16* x_lo  = x_hi + 8388608;                   // 16MB, dead after QKV gemm
  u16* wq_hi = x_lo + 8388608;
  u16* wq_lo = wq_hi + 3145728;
  u16* wp_hi = wq_lo + 3145728;
  u16* wp_lo = wp_hi + 1048576;
  u16* ao_hi = wp_lo + 1048576;                  // 16MB
  u16* ao_lo = ao_hi + 8388608;                  // 16MB
  // aliases (source regions dead by the time these are written):
  u16* qh = x_hi;
  u16* ql = x_lo;
  u16* kh = (u16*)qf32;
  u16* kl = kh + 8388608;
  u16* vtb = (u16*)kf32;

  split_bf16<<<8192, 256, 0, stream>>>(x, x_hi, x_lo);
  split_bf16<<<3072, 256, 0, stream>>>(w_qkv, wq_hi, wq_lo);
  split_bf16<<<1024, 256, 0, stream>>>(w_proj, wp_hi, wp_lo);

  gemm_split_mfma<<<dim3(QKV_N / 128, M_ROWS / 128), 256, 0, stream>>>(
      x_hi, x_lo, wq_hi, wq_lo, b_qkv, qf32, kf32, vf32, M_ROWS, QKV_N, C_DIM);

  rms_split<<<32768, 256, 0, stream>>>(qf32, qn_w, qh, ql);
  rms_split<<<32768, 256, 0, stream>>>(kf32, kn_w, kh, kl);
  vtrans<<<dim3(16, 128), 256, 0, stream>>>(vf32, vtb);

  flash_mfma<<<dim3(16, 128), 256, 0, stream>>>(qh, ql, kh, kl, vtb, ao_hi, ao_lo);

  gemm_split_mfma<<<dim3(C_DIM / 128, M_ROWS / 128), 256, 0, stream>>>(
      ao_hi, ao_lo, wp_hi, wp_lo, b_proj, out, out, out, M_ROWS, C_DIM, C_DIM);
}